// Round 5
// baseline (100.367 us; speedup 1.0000x reference)
//
#include <hip/hip_runtime.h>

#define HF 240      // fine height/width
#define HC 60       // coarse height/width
#define STRIDEF 4   // HF/HC
#define PADW 2      // WINDOW//2
#define WIN 5
#define CC 256      // C_COARSE
#define CF 128      // C_FINE
#define NPOS 25     // WIN*WIN
#define NPX (HF*HF) // 57600 pixels per image
#define MPB 16      // matches per block in k_coarse
#define PXT 64      // px per k_tgemm tile

typedef __bf16 bf16x8 __attribute__((ext_vector_type(8)));
typedef __bf16 bf16x4 __attribute__((ext_vector_type(4)));
typedef float  f32x4  __attribute__((ext_vector_type(4)));

// ---------------------------------------------------------------------------
// K1: grid=128 (j), block=256 (k).
//   Wm1h[j][k<128] = bf16(W_merge[j][k])
//   W_effT[k][j]   = sum_q Wm2[j][q] * W_dp[q][k]
//   b_eff[j]       = Wm2[j]·b_dp + b_merge[j]
// ---------------------------------------------------------------------------
__global__ void k_prep(const float* __restrict__ W_dp, const float* __restrict__ b_dp,
                       const float* __restrict__ W_merge, const float* __restrict__ b_merge,
                       __bf16* __restrict__ Wm1h, float* __restrict__ W_effT,
                       float* __restrict__ b_eff) {
    const int j = blockIdx.x;    // 0..127 output channel
    const int k = threadIdx.x;   // 0..255 coarse dim
    const float* wm2 = W_merge + (size_t)j * (2 * CF) + CF;

    float acc = 0.f, accb = 0.f;
    for (int q = 0; q < CF; ++q) {
        const float wq = wm2[q];                    // wave-uniform
        acc  += wq * W_dp[(size_t)q * CC + k];      // coalesced
        accb += wq * b_dp[q];
    }
    W_effT[(size_t)k * CF + j] = acc;

    if (k < CF)
        Wm1h[(size_t)j * CF + k] = (__bf16)W_merge[(size_t)j * (2 * CF) + k];
    if (k == 0)
        b_eff[j] = accb + b_merge[j];
}

// ---------------------------------------------------------------------------
// K2: c_all[m][j] = b_eff[j] + sum_k W_eff[j][k] * coarse_vec(m)[k]
// ---------------------------------------------------------------------------
__global__ void k_coarse(const float* __restrict__ c1, const float* __restrict__ c2,
                         const int* __restrict__ bidx, const int* __restrict__ ridx,
                         const int* __restrict__ cidx, int M,
                         const float* __restrict__ W_effT, const float* __restrict__ b_eff,
                         float* __restrict__ c_all) {
    const int m0 = blockIdx.x * MPB;
    const int j  = threadIdx.x;  // 0..127
    const int twoM = 2 * M;
    __shared__ float v[MPB * CC];   // 16 KB

    const int nm = (twoM - m0) < MPB ? (twoM - m0) : MPB;
    for (int mm = 0; mm < nm; ++mm) {
        int m = m0 + mm;
        const float* src;
        if (m < M) src = c1 + ((size_t)bidx[m] * (HC * HC) + ridx[m]) * CC;
        else       src = c2 + ((size_t)bidx[m - M] * (HC * HC) + cidx[m - M]) * CC;
        v[mm * CC + j]      = src[j];
        v[mm * CC + j + CF] = src[j + CF];
    }
    __syncthreads();

    float acc[MPB];
    const float be = b_eff[j];
    #pragma unroll
    for (int mm = 0; mm < MPB; ++mm) acc[mm] = be;

    for (int k = 0; k < CC; k += 4) {
        float w0 = W_effT[(k + 0) * CF + j];
        float w1 = W_effT[(k + 1) * CF + j];
        float w2 = W_effT[(k + 2) * CF + j];
        float w3 = W_effT[(k + 3) * CF + j];
        #pragma unroll
        for (int mm = 0; mm < MPB; ++mm) {
            const f32x4 vv = *(const f32x4*)&v[mm * CC + k];
            acc[mm] += w0 * vv.x + w1 * vv.y + w2 * vv.z + w3 * vv.w;
        }
    }
    for (int mm = 0; mm < nm; ++mm)
        c_all[(size_t)(m0 + mm) * CF + j] = acc[mm];
}

// ---------------------------------------------------------------------------
// KTG: fused transpose + GEMM, register-blocked.
// Per block: 64px x 128ch fp32 tile -> bf16 LDS -> V[px][j] = patch · Wm1^T.
// Thread (lo16,hi,w): loads 8 float4 = 8ch x 4px (coalesced 256B/instr),
// register-transposes, writes 4x ds_write_b128 (8 contiguous ch per px).
// LDS layout: patch[px][chunk^swz], chunk = 16B of 8 ch; swz = px&15.
// Both write and read spread uniformly over banks (LDS-BW floor).
// grid=(900,4), block=256.
// ---------------------------------------------------------------------------
__global__ __launch_bounds__(256) void k_tgemm(
    const float* __restrict__ f1, const float* __restrict__ f2,
    const __bf16* __restrict__ Wm1h, __bf16* __restrict__ V) {

    const int slot = blockIdx.y;
    const float* src = (slot >= 2 ? f2 : f1) + (size_t)(slot & 1) * CF * NPX;
    const int px0 = blockIdx.x * PXT;
    const int t  = threadIdx.x;
    const int l  = t & 63;
    const int w  = t >> 6;
    const int lo16 = l & 15;
    const int hi   = l >> 4;

    __shared__ __attribute__((aligned(16))) __bf16 patch[PXT * CF];   // 16 KB

    // B fragments: Wm1[j][k], j = w*32 + nt2*16 + lo16 (L2-resident)
    bf16x8 bfrag[2][4];
    #pragma unroll
    for (int nt2 = 0; nt2 < 2; ++nt2) {
        const int j = w * 32 + nt2 * 16 + lo16;
        #pragma unroll
        for (int kt = 0; kt < 4; ++kt)
            bfrag[nt2][kt] = *reinterpret_cast<const bf16x8*>(Wm1h + (size_t)j * CF + kt * 32 + hi * 8);
    }

    // phase 1: 8 float4 loads (ch = k0..k0+7, px = pxl..pxl+3), reg transpose,
    // 4x b128 swizzled LDS writes
    const int pxl = 4 * lo16;
    const int k0  = w * 32 + hi * 8;        // chunk base ch; k0>>3 = w*4+hi
    f32x4 vv[8];
    #pragma unroll
    for (int e = 0; e < 8; ++e)
        vv[e] = *reinterpret_cast<const f32x4*>(src + (size_t)(k0 + e) * NPX + px0 + pxl);

    #pragma unroll
    for (int i = 0; i < 4; ++i) {
        const int px = pxl + i;
        bf16x8 pk;
        pk[0] = (__bf16)vv[0][i]; pk[1] = (__bf16)vv[1][i];
        pk[2] = (__bf16)vv[2][i]; pk[3] = (__bf16)vv[3][i];
        pk[4] = (__bf16)vv[4][i]; pk[5] = (__bf16)vv[5][i];
        pk[6] = (__bf16)vv[6][i]; pk[7] = (__bf16)vv[7][i];
        const int chunk = ((w * 4 + hi) ^ (px & 15)) & 15;
        *reinterpret_cast<bf16x8*>(&patch[px * CF + (chunk << 3)]) = pk;
    }
    __syncthreads();

    // phase 2: MFMA, A-frags via swizzled b128 reads
    f32x4 acc[4][2];
    #pragma unroll
    for (int mt = 0; mt < 4; ++mt)
        #pragma unroll
        for (int nt2 = 0; nt2 < 2; ++nt2)
            acc[mt][nt2] = (f32x4){0.f, 0.f, 0.f, 0.f};

    #pragma unroll
    for (int kt = 0; kt < 4; ++kt) {
        #pragma unroll
        for (int mt = 0; mt < 4; ++mt) {
            const int px = mt * 16 + lo16;
            const int chunk = ((kt * 4 + hi) ^ (px & 15)) & 15;
            bf16x8 a = *reinterpret_cast<const bf16x8*>(&patch[px * CF + (chunk << 3)]);
            #pragma unroll
            for (int nt2 = 0; nt2 < 2; ++nt2)
                acc[mt][nt2] = __builtin_amdgcn_mfma_f32_16x16x32_bf16(a, bfrag[nt2][kt], acc[mt][nt2], 0, 0, 0);
        }
    }

    // epilogue: V[slot][px][j] = bf16(acc)
    __bf16* Vp = V + ((size_t)slot * NPX + px0) * CF;
    #pragma unroll
    for (int mt = 0; mt < 4; ++mt) {
        #pragma unroll
        for (int nt2 = 0; nt2 < 2; ++nt2) {
            const int j = w * 32 + nt2 * 16 + lo16;
            #pragma unroll
            for (int reg = 0; reg < 4; ++reg) {
                const int px = mt * 16 + hi * 4 + reg;
                Vp[(size_t)px * CF + j] = (__bf16)acc[mt][nt2][reg];
            }
        }
    }
}

// ---------------------------------------------------------------------------
// K4: pure gather-add stream: out[m][p][j] = V[slot][y,x][j] + c_all[m][j]
// grid = 2M, block = 256. No LDS, no sync.
// ---------------------------------------------------------------------------
__global__ __launch_bounds__(256) void k_gather(
    const __bf16* __restrict__ V,
    const int* __restrict__ bidx, const int* __restrict__ ridx,
    const int* __restrict__ cidx, int M,
    const float* __restrict__ c_all, float* __restrict__ out) {

    const int m = blockIdx.x;
    const int t = threadIdx.x;
    const int g  = t >> 5;    // row group 0..7
    const int l32 = t & 31;   // covers 128 ch as 32 float4

    int b, lin, ii;
    if (m < M) { ii = 0; b = bidx[m];     lin = ridx[m]; }
    else       { ii = 1; b = bidx[m - M]; lin = cidx[m - M]; }
    const int slot = ii * 2 + b;
    const int r  = lin / HC, c = lin - r * HC;
    const int y0 = r * STRIDEF - PADW;
    const int x0 = c * STRIDEF - PADW;

    const f32x4 c4 = *reinterpret_cast<const f32x4*>(c_all + (size_t)m * CF + l32 * 4);
    const __bf16* Vb = V + (size_t)slot * NPX * CF;
    float* ob = out + (size_t)m * (NPOS * CF) + l32 * 4;

    #pragma unroll
    for (int pass = 0; pass < 4; ++pass) {
        const int p = pass * 8 + g;
        if (p < NPOS) {
            const int wy = (p * 13) >> 6;      // p/5 for p<32
            const int wx = p - wy * WIN;
            const int y = y0 + wy, x = x0 + wx;
            f32x4 o = c4;
            if (y >= 0 && x >= 0) {
                const bf16x4 v = *reinterpret_cast<const bf16x4*>(Vb + (size_t)(y * HF + x) * CF + l32 * 4);
                o.x += (float)v.x; o.y += (float)v.y; o.z += (float)v.z; o.w += (float)v.w;
            }
            *reinterpret_cast<f32x4*>(ob + (size_t)p * CF) = o;
        }
    }
}

// ---------------------------------------------------------------------------
// Fallback main (R2 path): gather directly from fp32 NCHW images.
// ---------------------------------------------------------------------------
__global__ __launch_bounds__(256) void k_main_direct(
    const float* __restrict__ f1, const float* __restrict__ f2,
    const int* __restrict__ bidx, const int* __restrict__ ridx,
    const int* __restrict__ cidx, int M,
    const __bf16* __restrict__ Wm1h, const float* __restrict__ c_all,
    float* __restrict__ out) {

    const int m = blockIdx.x;
    const int t = threadIdx.x;
    const int l    = t & 63;
    const int wv   = t >> 6;
    const int lo16 = l & 15;
    const int hi   = l >> 4;

    __shared__ __bf16 patch[32 * CF];

    bf16x8 bfrag[2][4];
    #pragma unroll
    for (int nt2 = 0; nt2 < 2; ++nt2) {
        const int j = wv * 32 + nt2 * 16 + lo16;
        #pragma unroll
        for (int kt = 0; kt < 4; ++kt)
            bfrag[nt2][kt] = *reinterpret_cast<const bf16x8*>(Wm1h + (size_t)j * CF + kt * 32 + hi * 8);
    }

    const float* img; int b, lin;
    if (m < M) { img = f1; b = bidx[m];     lin = ridx[m]; }
    else       { img = f2; b = bidx[m - M]; lin = cidx[m - M]; }
    const int r  = lin / HC, c = lin - r * HC;
    const int y0 = r * STRIDEF - PADW;
    const int x0 = c * STRIDEF - PADW;

    for (int task = t; task < CF * WIN; task += 256) {
        const int ch = task / WIN;
        const int wy = task - ch * WIN;
        const int y  = y0 + wy;
        const bool yok = (y >= 0);
        const float* rowp = img + (((size_t)b * CF + ch) * HF + (yok ? y : 0)) * HF;
        #pragma unroll
        for (int wx = 0; wx < WIN; ++wx) {
            const int x = x0 + wx;
            const float val = (yok && x >= 0) ? rowp[x] : 0.f;
            const int pos = wy * WIN + wx;
            patch[pos * CF + (ch ^ ((pos & 7) << 3))] = (__bf16)val;
        }
    }
    __syncthreads();

    f32x4 acc[2][2];
    #pragma unroll
    for (int mt = 0; mt < 2; ++mt)
        #pragma unroll
        for (int nt2 = 0; nt2 < 2; ++nt2)
            acc[mt][nt2] = (f32x4){0.f, 0.f, 0.f, 0.f};

    const int swz = (lo16 & 7) << 3;
    #pragma unroll
    for (int kt = 0; kt < 4; ++kt) {
        const int koff = (kt * 32 + hi * 8) ^ swz;
        bf16x8 a0 = *reinterpret_cast<const bf16x8*>(&patch[ lo16       * CF + koff]);
        bf16x8 a1 = *reinterpret_cast<const bf16x8*>(&patch[(16 + lo16) * CF + koff]);
        #pragma unroll
        for (int nt2 = 0; nt2 < 2; ++nt2) {
            acc[0][nt2] = __builtin_amdgcn_mfma_f32_16x16x32_bf16(a0, bfrag[nt2][kt], acc[0][nt2], 0, 0, 0);
            acc[1][nt2] = __builtin_amdgcn_mfma_f32_16x16x32_bf16(a1, bfrag[nt2][kt], acc[1][nt2], 0, 0, 0);
        }
    }

    float* ob = out + (size_t)m * (NPOS * CF);
    #pragma unroll
    for (int nt2 = 0; nt2 < 2; ++nt2) {
        const int j  = wv * 32 + nt2 * 16 + lo16;
        const float cv = c_all[(size_t)m * CF + j];
        #pragma unroll
        for (int mt = 0; mt < 2; ++mt) {
            #pragma unroll
            for (int reg = 0; reg < 4; ++reg) {
                const int p = mt * 16 + hi * 4 + reg;
                if (p < NPOS)
                    ob[(size_t)p * CF + j] = acc[mt][nt2][reg] + cv;
            }
        }
    }
}

// ---------------------------------------------------------------------------
extern "C" void kernel_launch(void* const* d_in, const int* in_sizes, int n_in,
                              void* d_out, int out_size, void* d_ws, size_t ws_size,
                              hipStream_t stream) {
    const float* c1      = (const float*)d_in[0];
    const float* c2      = (const float*)d_in[1];
    const float* f1      = (const float*)d_in[2];
    const float* f2      = (const float*)d_in[3];
    const int*   bidx    = (const int*)d_in[4];
    const int*   ridx    = (const int*)d_in[5];
    const int*   cidx    = (const int*)d_in[6];
    const float* W_dp    = (const float*)d_in[9];
    const float* b_dp    = (const float*)d_in[10];
    const float* W_merge = (const float*)d_in[11];
    const float* b_merge = (const float*)d_in[12];
    const int M = in_sizes[4];

    char* ws = (char*)d_ws;
    __bf16* Wm1h  = (__bf16*)(ws);                //  32 KB
    float* W_effT = (float*)(ws + (64 << 10));    // 128 KB
    float* b_eff  = (float*)(ws + (192 << 10));   // 512 B
    float* c_all  = (float*)(ws + (256 << 10));   // 2M*128*4 ~ 3.07 MB
    __bf16* V     = (__bf16*)(ws + (4 << 20));    // 4*57600*128*2 = 58.98 MB

    const size_t need_V = (size_t)(4 << 20) + (size_t)4 * NPX * CF * 2;

    hipLaunchKernelGGL(k_prep, dim3(CF), dim3(CC), 0, stream,
                       W_dp, b_dp, W_merge, b_merge, Wm1h, W_effT, b_eff);
    hipLaunchKernelGGL(k_coarse, dim3((2 * M + MPB - 1) / MPB), dim3(CF), 0, stream,
                       c1, c2, bidx, ridx, cidx, M, W_effT, b_eff, c_all);

    if (ws_size >= need_V) {
        hipLaunchKernelGGL(k_tgemm, dim3(NPX / PXT, 4), dim3(256), 0, stream,
                           f1, f2, Wm1h, V);
        hipLaunchKernelGGL(k_gather, dim3(2 * M), dim3(256), 0, stream,
                           V, bidx, ridx, cidx, M, c_all, (float*)d_out);
    } else {
        hipLaunchKernelGGL(k_main_direct, dim3(2 * M), dim3(256), 0, stream,
                           f1, f2, bidx, ridx, cidx, M, Wm1h, c_all, (float*)d_out);
    }
}

// Round 6
// 95.336 us; speedup vs baseline: 1.0528x; 1.0528x over previous
//
#include <hip/hip_runtime.h>

#define HF 240      // fine height/width
#define HC 60       // coarse height/width
#define STRIDEF 4   // HF/HC
#define PADW 2      // WINDOW//2
#define WIN 5
#define CC 256      // C_COARSE
#define CF 128      // C_FINE
#define NPOS 25     // WIN*WIN
#define NPX (HF*HF) // 57600 pixels per image
#define MPB 16      // matches per block in k_coarse
#define TPX 128     // px per k_tgemm block tile
#define KCH 32      // ch per K-chunk
#define NCHK 4      // 128/KCH

typedef __bf16 bf16x8 __attribute__((ext_vector_type(8)));
typedef __bf16 bf16x4 __attribute__((ext_vector_type(4)));
typedef float  f32x4  __attribute__((ext_vector_type(4)));
typedef float  f32x2  __attribute__((ext_vector_type(2)));

// ---------------------------------------------------------------------------
// K1: grid=128 (j), block=256 (k).
//   Wm1h[j][k<128] = bf16(W_merge[j][k])
//   W_effT[k][j]   = sum_q Wm2[j][q] * W_dp[q][k]
//   b_eff[j]       = Wm2[j]·b_dp + b_merge[j]
// ---------------------------------------------------------------------------
__global__ void k_prep(const float* __restrict__ W_dp, const float* __restrict__ b_dp,
                       const float* __restrict__ W_merge, const float* __restrict__ b_merge,
                       __bf16* __restrict__ Wm1h, float* __restrict__ W_effT,
                       float* __restrict__ b_eff) {
    const int j = blockIdx.x;    // 0..127 output channel
    const int k = threadIdx.x;   // 0..255 coarse dim
    const float* wm2 = W_merge + (size_t)j * (2 * CF) + CF;

    float acc = 0.f, accb = 0.f;
    for (int q = 0; q < CF; ++q) {
        const float wq = wm2[q];                    // wave-uniform
        acc  += wq * W_dp[(size_t)q * CC + k];      // coalesced
        accb += wq * b_dp[q];
    }
    W_effT[(size_t)k * CF + j] = acc;

    if (k < CF)
        Wm1h[(size_t)j * CF + k] = (__bf16)W_merge[(size_t)j * (2 * CF) + k];
    if (k == 0)
        b_eff[j] = accb + b_merge[j];
}

// ---------------------------------------------------------------------------
// K2: c_all[m][j] = b_eff[j] + sum_k W_eff[j][k] * coarse_vec(m)[k]
// ---------------------------------------------------------------------------
__global__ void k_coarse(const float* __restrict__ c1, const float* __restrict__ c2,
                         const int* __restrict__ bidx, const int* __restrict__ ridx,
                         const int* __restrict__ cidx, int M,
                         const float* __restrict__ W_effT, const float* __restrict__ b_eff,
                         float* __restrict__ c_all) {
    const int m0 = blockIdx.x * MPB;
    const int j  = threadIdx.x;  // 0..127
    const int twoM = 2 * M;
    __shared__ float v[MPB * CC];   // 16 KB

    const int nm = (twoM - m0) < MPB ? (twoM - m0) : MPB;
    for (int mm = 0; mm < nm; ++mm) {
        int m = m0 + mm;
        const float* src;
        if (m < M) src = c1 + ((size_t)bidx[m] * (HC * HC) + ridx[m]) * CC;
        else       src = c2 + ((size_t)bidx[m - M] * (HC * HC) + cidx[m - M]) * CC;
        v[mm * CC + j]      = src[j];
        v[mm * CC + j + CF] = src[j + CF];
    }
    __syncthreads();

    float acc[MPB];
    const float be = b_eff[j];
    #pragma unroll
    for (int mm = 0; mm < MPB; ++mm) acc[mm] = be;

    for (int k = 0; k < CC; k += 4) {
        float w0 = W_effT[(k + 0) * CF + j];
        float w1 = W_effT[(k + 1) * CF + j];
        float w2 = W_effT[(k + 2) * CF + j];
        float w3 = W_effT[(k + 3) * CF + j];
        #pragma unroll
        for (int mm = 0; mm < MPB; ++mm) {
            const f32x4 vv = *(const f32x4*)&v[mm * CC + k];
            acc[mm] += w0 * vv.x + w1 * vv.y + w2 * vv.z + w3 * vv.w;
        }
    }
    for (int mm = 0; mm < nm; ++mm)
        c_all[(size_t)(m0 + mm) * CF + j] = acc[mm];
}

// ---------------------------------------------------------------------------
// KTG v3: pipelined K-chunked transpose+GEMM.
// Block tile: 128 px (M) x 128 ch (K), K-chunks of 32, double-buffered LDS.
//   loads:  per chunk, wave w instr e: ch = c*32 + w*8 + e, 64 lanes cover
//           128 px as float2 -> 512B contiguous per instr.
//   LDS:    chunk [rp=px/2][8 slots x 16B], slot S=(chblk*2+(px&1))^(rp&7)
//           -> bank-conflict floor for both b128 write and read.
//   MFMA:   wave w owns j = w*32..+31 via even/odd pairing
//           (N-tile nt2 covers rows j = w*32 + 2*lo16 + nt2).
//   stores: pack (j_even, j_odd) -> bf16x2 dword, standard V[px][j] layout.
// grid = (450, 4), block = 256.
// ---------------------------------------------------------------------------
__global__ __launch_bounds__(256) void k_tgemm(
    const float* __restrict__ f1, const float* __restrict__ f2,
    const __bf16* __restrict__ Wm1h, __bf16* __restrict__ V) {

    const int slot = blockIdx.y;
    const float* src = (slot >= 2 ? f2 : f1) + (size_t)(slot & 1) * CF * NPX;
    const int px0 = blockIdx.x * TPX;
    const int t  = threadIdx.x;
    const int l  = t & 63;
    const int w  = t >> 6;
    const int lo16 = l & 15;
    const int hi   = l >> 4;

    __shared__ __attribute__((aligned(16))) __bf16 chk[2][(TPX / 2) * 64]; // 2 x 8 KB

    // B fragments: row j = w*32 + 2*lo16 + nt2 (even/odd pairing), k-slice hi*8..+7
    bf16x8 bfrag[2][NCHK];
    #pragma unroll
    for (int nt2 = 0; nt2 < 2; ++nt2) {
        const int j = w * 32 + 2 * lo16 + nt2;
        #pragma unroll
        for (int c = 0; c < NCHK; ++c)
            bfrag[nt2][c] = *reinterpret_cast<const bf16x8*>(
                Wm1h + (size_t)j * CF + c * KCH + hi * 8);
    }

    f32x2 vva[8], vvb[8];   // double-buffered load regs (static names, rule #20)

#define LOAD_CHUNK(c, vbuf)                                                    \
    {                                                                          \
        const int ch0 = (c) * KCH + w * 8;                                     \
        _Pragma("unroll")                                                      \
        for (int e = 0; e < 8; ++e)                                            \
            vbuf[e] = *reinterpret_cast<const f32x2*>(                         \
                src + (size_t)(ch0 + e) * NPX + px0 + 2 * l);                  \
    }

#define WRITE_CHUNK(buf, vbuf)                                                 \
    {                                                                          \
        _Pragma("unroll")                                                      \
        for (int i = 0; i < 2; ++i) {                                          \
            const int px = 2 * l + i;                                          \
            bf16x8 pk;                                                         \
            _Pragma("unroll")                                                  \
            for (int e = 0; e < 8; ++e) pk[e] = (__bf16)vbuf[e][i];            \
            const int rp = px >> 1;  /* == l */                                \
            const int S  = (w * 2 + (px & 1)) ^ (rp & 7);                      \
            *reinterpret_cast<bf16x8*>(&chk[buf][rp * 64 + S * 8]) = pk;       \
        }                                                                      \
    }

    f32x4 acc[8][2];
    #pragma unroll
    for (int mt = 0; mt < 8; ++mt) {
        acc[mt][0] = (f32x4){0.f, 0.f, 0.f, 0.f};
        acc[mt][1] = (f32x4){0.f, 0.f, 0.f, 0.f};
    }

    LOAD_CHUNK(0, vva);

    #pragma unroll
    for (int c = 0; c < NCHK; ++c) {
        const int buf = c & 1;
        // issue next chunk's loads before consuming current (overlap)
        if (buf == 0) {
            if (c + 1 < NCHK) LOAD_CHUNK(c + 1, vvb);
            WRITE_CHUNK(0, vva);
        } else {
            if (c + 1 < NCHK) LOAD_CHUNK(c + 1, vva);
            WRITE_CHUNK(1, vvb);
        }
        __syncthreads();

        #pragma unroll
        for (int mt = 0; mt < 8; ++mt) {
            const int px = mt * 16 + lo16;
            const int rp = px >> 1;
            const int S  = (hi * 2 + (px & 1)) ^ (rp & 7);
            const bf16x8 a = *reinterpret_cast<const bf16x8*>(&chk[buf][rp * 64 + S * 8]);
            acc[mt][0] = __builtin_amdgcn_mfma_f32_16x16x32_bf16(a, bfrag[0][c], acc[mt][0], 0, 0, 0);
            acc[mt][1] = __builtin_amdgcn_mfma_f32_16x16x32_bf16(a, bfrag[1][c], acc[mt][1], 0, 0, 0);
        }
        __syncthreads();
    }

    // epilogue: V[px][j], dword = (j_even, j_odd) bf16x2
    uint* Vp = (uint*)(V + ((size_t)slot * NPX + px0) * CF);
    const int dcol = w * 16 + lo16;   // dword column = (w*32 + 2*lo16)/2
    #pragma unroll
    for (int mt = 0; mt < 8; ++mt) {
        #pragma unroll
        for (int reg = 0; reg < 4; ++reg) {
            const int px = mt * 16 + hi * 4 + reg;
            union { uint u; __bf16 h[2]; } cv;
            cv.h[0] = (__bf16)acc[mt][0][reg];
            cv.h[1] = (__bf16)acc[mt][1][reg];
            Vp[(size_t)px * 64 + dcol] = cv.u;
        }
    }
#undef LOAD_CHUNK
#undef WRITE_CHUNK
}

// ---------------------------------------------------------------------------
// K4: pure gather-add stream: out[m][p][j] = V[slot][y,x][j] + c_all[m][j]
// grid = 2M, block = 256. No LDS, no sync.
// ---------------------------------------------------------------------------
__global__ __launch_bounds__(256) void k_gather(
    const __bf16* __restrict__ V,
    const int* __restrict__ bidx, const int* __restrict__ ridx,
    const int* __restrict__ cidx, int M,
    const float* __restrict__ c_all, float* __restrict__ out) {

    const int m = blockIdx.x;
    const int t = threadIdx.x;
    const int g  = t >> 5;    // row group 0..7
    const int l32 = t & 31;   // covers 128 ch as 32 float4

    int b, lin, ii;
    if (m < M) { ii = 0; b = bidx[m];     lin = ridx[m]; }
    else       { ii = 1; b = bidx[m - M]; lin = cidx[m - M]; }
    const int slot = ii * 2 + b;
    const int r  = lin / HC, c = lin - r * HC;
    const int y0 = r * STRIDEF - PADW;
    const int x0 = c * STRIDEF - PADW;

    const f32x4 c4 = *reinterpret_cast<const f32x4*>(c_all + (size_t)m * CF + l32 * 4);
    const __bf16* Vb = V + (size_t)slot * NPX * CF;
    float* ob = out + (size_t)m * (NPOS * CF) + l32 * 4;

    #pragma unroll
    for (int pass = 0; pass < 4; ++pass) {
        const int p = pass * 8 + g;
        if (p < NPOS) {
            const int wy = (p * 13) >> 6;      // p/5 for p<32
            const int wx = p - wy * WIN;
            const int y = y0 + wy, x = x0 + wx;
            f32x4 o = c4;
            if (y >= 0 && x >= 0) {
                const bf16x4 v = *reinterpret_cast<const bf16x4*>(Vb + (size_t)(y * HF + x) * CF + l32 * 4);
                o.x += (float)v.x; o.y += (float)v.y; o.z += (float)v.z; o.w += (float)v.w;
            }
            *reinterpret_cast<f32x4*>(ob + (size_t)p * CF) = o;
        }
    }
}

// ---------------------------------------------------------------------------
// Fallback main (R2 path): gather directly from fp32 NCHW images.
// ---------------------------------------------------------------------------
__global__ __launch_bounds__(256) void k_main_direct(
    const float* __restrict__ f1, const float* __restrict__ f2,
    const int* __restrict__ bidx, const int* __restrict__ ridx,
    const int* __restrict__ cidx, int M,
    const __bf16* __restrict__ Wm1h, const float* __restrict__ c_all,
    float* __restrict__ out) {

    const int m = blockIdx.x;
    const int t = threadIdx.x;
    const int l    = t & 63;
    const int wv   = t >> 6;
    const int lo16 = l & 15;
    const int hi   = l >> 4;

    __shared__ __bf16 patch[32 * CF];

    bf16x8 bfrag[2][4];
    #pragma unroll
    for (int nt2 = 0; nt2 < 2; ++nt2) {
        const int j = wv * 32 + nt2 * 16 + lo16;
        #pragma unroll
        for (int kt = 0; kt < 4; ++kt)
            bfrag[nt2][kt] = *reinterpret_cast<const bf16x8*>(Wm1h + (size_t)j * CF + kt * 32 + hi * 8);
    }

    const float* img; int b, lin;
    if (m < M) { img = f1; b = bidx[m];     lin = ridx[m]; }
    else       { img = f2; b = bidx[m - M]; lin = cidx[m - M]; }
    const int r  = lin / HC, c = lin - r * HC;
    const int y0 = r * STRIDEF - PADW;
    const int x0 = c * STRIDEF - PADW;

    for (int task = t; task < CF * WIN; task += 256) {
        const int ch = task / WIN;
        const int wy = task - ch * WIN;
        const int y  = y0 + wy;
        const bool yok = (y >= 0);
        const float* rowp = img + (((size_t)b * CF + ch) * HF + (yok ? y : 0)) * HF;
        #pragma unroll
        for (int wx = 0; wx < WIN; ++wx) {
            const int x = x0 + wx;
            const float val = (yok && x >= 0) ? rowp[x] : 0.f;
            const int pos = wy * WIN + wx;
            patch[pos * CF + (ch ^ ((pos & 7) << 3))] = (__bf16)val;
        }
    }
    __syncthreads();

    f32x4 acc[2][2];
    #pragma unroll
    for (int mt = 0; mt < 2; ++mt)
        #pragma unroll
        for (int nt2 = 0; nt2 < 2; ++nt2)
            acc[mt][nt2] = (f32x4){0.f, 0.f, 0.f, 0.f};

    const int swz = (lo16 & 7) << 3;
    #pragma unroll
    for (int kt = 0; kt < 4; ++kt) {
        const int koff = (kt * 32 + hi * 8) ^ swz;
        bf16x8 a0 = *reinterpret_cast<const bf16x8*>(&patch[ lo16       * CF + koff]);
        bf16x8 a1 = *reinterpret_cast<const bf16x8*>(&patch[(16 + lo16) * CF + koff]);
        #pragma unroll
        for (int nt2 = 0; nt2 < 2; ++nt2) {
            acc[0][nt2] = __builtin_amdgcn_mfma_f32_16x16x32_bf16(a0, bfrag[nt2][kt], acc[0][nt2], 0, 0, 0);
            acc[1][nt2] = __builtin_amdgcn_mfma_f32_16x16x32_bf16(a1, bfrag[nt2][kt], acc[1][nt2], 0, 0, 0);
        }
    }

    float* ob = out + (size_t)m * (NPOS * CF);
    #pragma unroll
    for (int nt2 = 0; nt2 < 2; ++nt2) {
        const int j  = wv * 32 + nt2 * 16 + lo16;
        const float cv = c_all[(size_t)m * CF + j];
        #pragma unroll
        for (int mt = 0; mt < 2; ++mt) {
            #pragma unroll
            for (int reg = 0; reg < 4; ++reg) {
                const int p = mt * 16 + hi * 4 + reg;
                if (p < NPOS)
                    ob[(size_t)p * CF + j] = acc[mt][nt2][reg] + cv;
            }
        }
    }
}

// ---------------------------------------------------------------------------
extern "C" void kernel_launch(void* const* d_in, const int* in_sizes, int n_in,
                              void* d_out, int out_size, void* d_ws, size_t ws_size,
                              hipStream_t stream) {
    const float* c1      = (const float*)d_in[0];
    const float* c2      = (const float*)d_in[1];
    const float* f1      = (const float*)d_in[2];
    const float* f2      = (const float*)d_in[3];
    const int*   bidx    = (const int*)d_in[4];
    const int*   ridx    = (const int*)d_in[5];
    const int*   cidx    = (const int*)d_in[6];
    const float* W_dp    = (const float*)d_in[9];
    const float* b_dp    = (const float*)d_in[10];
    const float* W_merge = (const float*)d_in[11];
    const float* b_merge = (const float*)d_in[12];
    const int M = in_sizes[4];

    char* ws = (char*)d_ws;
    __bf16* Wm1h  = (__bf16*)(ws);                //  32 KB
    float* W_effT = (float*)(ws + (64 << 10));    // 128 KB
    float* b_eff  = (float*)(ws + (192 << 10));   // 512 B
    float* c_all  = (float*)(ws + (256 << 10));   // 2M*128*4 ~ 3.07 MB
    __bf16* V     = (__bf16*)(ws + (4 << 20));    // 4*57600*128*2 = 58.98 MB

    const size_t need_V = (size_t)(4 << 20) + (size_t)4 * NPX * CF * 2;

    hipLaunchKernelGGL(k_prep, dim3(CF), dim3(CC), 0, stream,
                       W_dp, b_dp, W_merge, b_merge, Wm1h, W_effT, b_eff);
    hipLaunchKernelGGL(k_coarse, dim3((2 * M + MPB - 1) / MPB), dim3(CF), 0, stream,
                       c1, c2, bidx, ridx, cidx, M, W_effT, b_eff, c_all);

    if (ws_size >= need_V) {
        hipLaunchKernelGGL(k_tgemm, dim3(NPX / TPX, 4), dim3(256), 0, stream,
                           f1, f2, Wm1h, V);
        hipLaunchKernelGGL(k_gather, dim3(2 * M), dim3(256), 0, stream,
                           V, bidx, ridx, cidx, M, c_all, (float*)d_out);
    } else {
        hipLaunchKernelGGL(k_main_direct, dim3(2 * M), dim3(256), 0, stream,
                           f1, f2, bidx, ridx, cidx, M, Wm1h, c_all, (float*)d_out);
    }
}